// Round 6
// baseline (613.780 us; speedup 1.0000x reference)
//
#include <hip/hip_runtime.h>

// RunningCenters R12: vectorize the accum hot loop (Guideline 13).
// R10/R11 both pinned at ~350us, VALUBusy 3%, 1.9 GB/s/CU -- scalar 4B
// loads cap per-CU request concurrency (m13 f4 copy: 24.6 GB/s/CU).
// Change: 8 points per wave-instr, f4 (16B) NT load per lane; LDS class
// stride padded to 33 floats so the 4 ds_add_f32 per lane spread banks
// ((c+4q+k)&31 instead of (4q+k)&31). Dump compacts 33->32; reduce
// unchanged. Even fully-serial worst case is now ~35us/wave (61 loads).

constexpr int C = 1000;
constexpr int D = 128;
constexpr int PARTS = 64;   // point partitions
constexpr int CHUNKS = 4;   // D chunks
constexpr int DC = 32;      // D / CHUNKS
constexpr int SPAD = 33;    // padded per-class LDS stride (floats)
constexpr int AT = 1024;    // accum threads (16 waves)
constexpr int NW = AT / 64; // waves per block = 16
constexpr int TP = 2048;    // points per staged tile (8 KB LDS)
constexpr int RT = 128;     // reduce threads (one per d)

typedef float f4 __attribute__((ext_vector_type(4)));

__device__ __forceinline__ void lds_fadd(float* p, float v) {
  __hip_atomic_fetch_add(p, v, __ATOMIC_RELAXED, __HIP_MEMORY_SCOPE_WORKGROUP);
}

// ws layout (poison-safe: both regions fully written before read):
// partial f32[PARTS*CHUNKS][C*DC]  @ 0         (32.768 MB)
// histp   u32[C*PARTS]             @ 33 MiB    (256 KB), layout c*PARTS+p

__global__ __launch_bounds__(AT) void accum_kernel(
    const float* __restrict__ x, const int* __restrict__ y,
    float* __restrict__ partial, unsigned int* __restrict__ histp, int N) {
  const int part = blockIdx.x >> 2;
  const int chunk = blockIdx.x & 3;
  const int d0 = chunk * DC;

  __shared__ float sums[C * SPAD];      // 132000 B
  __shared__ unsigned int hist[C];      //   4000 B
  __shared__ int ytile[TP];             //   8192 B  -> ~144 KB total
  for (int t = threadIdx.x; t < C * SPAD; t += AT) sums[t] = 0.f;
  if (chunk == 0)
    for (int t = threadIdx.x; t < C; t += AT) hist[t] = 0u;

  const int per = (N + PARTS - 1) / PARTS;
  const int beg = part * per;
  const int end = min(beg + per, N);
  const int wave = threadIdx.x >> 6;
  const int lane = threadIdx.x & 63;
  const int pt8 = lane >> 3;   // which of the 8 points in a wave-instr
  const int q = lane & 7;      // which f4 of the 32-float chunk

  const float* xq = x + d0 + 4 * q;

  for (int t0 = beg; t0 < end; t0 += TP) {
    const int nt = min(TP, end - t0);
    __syncthreads();  // protects ytile reuse + sums init on first pass
    for (int t = threadIdx.x; t < nt; t += AT) ytile[t] = y[t0 + t];
    __syncthreads();
    if (chunk == 0) {  // histogram once per tile from LDS copy (u32 atomics)
      for (int t = threadIdx.x; t < nt; t += AT) atomicAdd(&hist[ytile[t]], 1u);
    }
    if (nt == TP) {
      // fast path: 256 wave-instrs, 16 per wave
#pragma unroll 4
      for (int k = 0; k < TP / 8 / NW; ++k) {
        const int pt = (wave + k * NW) * 8 + pt8;
        const int c = ytile[pt];
        const f4 v = __builtin_nontemporal_load(
            (const f4*)(xq + (size_t)(t0 + pt) * D));
        float* s = &sums[c * SPAD + 4 * q];
        lds_fadd(s + 0, v[0]);
        lds_fadd(s + 1, v[1]);
        lds_fadd(s + 2, v[2]);
        lds_fadd(s + 3, v[3]);
      }
    } else {
      const int nfj = nt >> 3;  // full 8-point wave-instrs
      for (int j = wave; j < nfj; j += NW) {
        const int pt = j * 8 + pt8;
        const int c = ytile[pt];
        const f4 v = __builtin_nontemporal_load(
            (const f4*)(xq + (size_t)(t0 + pt) * D));
        float* s = &sums[c * SPAD + 4 * q];
        lds_fadd(s + 0, v[0]);
        lds_fadd(s + 1, v[1]);
        lds_fadd(s + 2, v[2]);
        lds_fadd(s + 3, v[3]);
      }
      if (wave == 0 && lane < 32) {  // <=7 tail points, lane owns one float
        for (int t = nfj * 8; t < nt; ++t) {
          const int c = ytile[t];
          lds_fadd(&sums[c * SPAD + lane],
                   x[(size_t)(t0 + t) * D + d0 + lane]);
        }
      }
    }
  }

  __syncthreads();
  // dump partial, compacting stride 33 -> 32 (coalesced dst)
  for (int t = threadIdx.x; t < C * DC; t += AT) {
    const int c = t >> 5, dd = t & 31;
    partial[(size_t)blockIdx.x * (C * DC) + t] = sums[c * SPAD + dd];
  }
  if (chunk == 0)
    for (int t = threadIdx.x; t < C; t += AT)
      histp[t * PARTS + part] = hist[t];
}

__global__ __launch_bounds__(RT) void reduce_kernel(
    const float* __restrict__ partial, const unsigned int* __restrict__ histp,
    const float* __restrict__ centers, const float* __restrict__ counter,
    float* __restrict__ out) {
  const int c = blockIdx.x;
  const int d = threadIdx.x;
  const int chunk = d >> 5;
  const int dd = d & 31;

  __shared__ unsigned int nsh;
  if (d < 64) {  // wave 0: count = sum of 64 partition hists (coalesced 256B)
    unsigned int v = histp[c * PARTS + d];
#pragma unroll
    for (int off = 32; off; off >>= 1) v += __shfl_down(v, off, 64);
    if (d == 0) nsh = v;
  }
  __syncthreads();
  const int n = (int)nsh;

  const size_t base = (size_t)chunk * (C * DC) + c * DC + dd;
  float s = 0.f;
#pragma unroll 8
  for (int p = 0; p < PARTS; ++p)
    s += partial[base + (size_t)p * (CHUNKS * C * DC)];

  const float cen = centers[c * D + d];
  float o;
  if (n > 0) {
    const float k = counter[0];
    o = (s / (float)n + cen * k) / (k + 1.f);
  } else {
    o = cen;
  }
  out[c * D + d] = o;
}

extern "C" void kernel_launch(void* const* d_in, const int* in_sizes, int n_in,
                              void* d_out, int out_size, void* d_ws, size_t ws_size,
                              hipStream_t stream) {
  const float* x       = (const float*)d_in[0];
  const int* y         = (const int*)d_in[1];
  const float* centers = (const float*)d_in[2];
  const float* counter = (const float*)d_in[3];
  float* out = (float*)d_out;
  const int N = in_sizes[1];

  float* partial      = (float*)d_ws;
  unsigned int* histp = (unsigned int*)((char*)d_ws + (33u << 20));

  accum_kernel<<<dim3(PARTS * CHUNKS), dim3(AT), 0, stream>>>(x, y, partial,
                                                              histp, N);
  reduce_kernel<<<dim3(C), dim3(RT), 0, stream>>>(partial, histp, centers,
                                                  counter, out);
}

// Round 7
// 445.028 us; speedup vs baseline: 1.3792x; 1.3792x over previous
//
#include <hip/hip_runtime.h>

// RunningCenters R13: ownership-routed streaming accumulation.
// Two HW laws from R9-R12: (1) LDS fp-atomic pipe ~3.2cy/lane -> 64M atomic
// lane-ops = 334us floor (R10/R11/R12 identical despite load shape);
// (2) random-row gather capped at ~6.6 GB/s/CU (MSHR ~40 x 64B / 900cy) ->
// class_sum ~147us floor (R0-R7 nulls). This structure avoids both:
// coalesced subtile staging into LDS (sequential DRAM) + NON-atomic
// ownership-partitioned RMW (wave w owns classes c%16==w) on the normal
// LDS pipe. Fully deterministic (no fp atomics). Staged layout XOR-swizzled
// so b128 writes and RMW reads are both bank-conflict-free. Transposed
// partial dump so reduce reads contiguous 32KB per class.

constexpr int C = 1000;
constexpr int D = 128;
constexpr int PARTS = 64;   // point partitions (blocks = PARTS*CHUNKS)
constexpr int CHUNKS = 4;   // D chunks per row
constexpr int DC = 32;      // floats per chunk
constexpr int SUB = 192;    // rows per staged subtile (LDS: 153.3 KB total)
constexpr int AT = 1024;    // accum threads (16 waves)
constexpr int NW = 16;      // waves per accum block
constexpr int HT = 1024;    // hist threads
constexpr int RT = 128;     // reduce threads (one per d)

typedef float f4 __attribute__((ext_vector_type(4)));

// ws layout (poison-safe: every region fully written before read):
// partial f32[C][PARTS][D]  @ 0        (32.768 MB), class-major
// histp   u32[C][PARTS]     @ 33 MiB   (256 KB)

__global__ __launch_bounds__(HT) void hist_kernel(
    const int* __restrict__ y, unsigned int* __restrict__ histp, int N) {
  __shared__ unsigned int h[C];
  for (int t = threadIdx.x; t < C; t += HT) h[t] = 0u;
  __syncthreads();
  const int b = blockIdx.x;
  const int chunkN = (N + PARTS - 1) / PARTS;
  const int beg = b * chunkN;
  const int e = min(beg + chunkN, N);
  for (int i = beg + threadIdx.x; i < e; i += HT) atomicAdd(&h[y[i]], 1u);
  __syncthreads();
  for (int t = threadIdx.x; t < C; t += HT)
    histp[(size_t)t * PARTS + b] = h[t];
}

__global__ __launch_bounds__(AT) void accum_kernel(
    const float* __restrict__ x, const int* __restrict__ y,
    float* __restrict__ partial, int N) {
  const int part = blockIdx.x >> 2;
  const int chunk = blockIdx.x & 3;
  const int d0 = chunk * DC;

  __shared__ float sums[C * DC];      // 128000 B
  __shared__ float staged[SUB * DC];  //  24576 B
  __shared__ int yt[SUB];             //    768 B  -> 153344 B total
  for (int t = threadIdx.x; t < C * DC; t += AT) sums[t] = 0.f;

  const int per = (N + PARTS - 1) / PARTS;
  const int beg = part * per;
  const int end = min(beg + per, N);
  const int wave = threadIdx.x >> 6;
  const int lane = threadIdx.x & 63;
  const int lr = lane >> 3;  // row-of-8 within a staging instr
  const int lq = lane & 7;   // f4 within the 32-float chunk

  for (int s0 = beg; s0 < end; s0 += SUB) {
    const int ns = min(SUB, end - s0);
    __syncthreads();  // prev subtile fully consumed (also covers sums init)
    if (threadIdx.x < SUB) {
      // sentinel (>=C) for clamped rows: never owned, never accumulated
      yt[threadIdx.x] = (threadIdx.x < ns) ? y[s0 + threadIdx.x] : 0x40000000;
    }
    // stage rows, coalesced f4; XOR-swizzle f4-column by row so the
    // b128 writes spread across banks (else 8-way conflict).
    for (int r8 = wave; r8 < SUB / 8; r8 += NW) {
      const int lrow = r8 * 8 + lr;
      const int srow = (lrow < ns) ? (s0 + lrow) : beg;  // clamp, no OOB
      const f4 v = __builtin_nontemporal_load(
          (const f4*)(x + (size_t)srow * D + d0) + lq);
      ((f4*)staged)[lrow * 8 + (lq ^ (lrow & 7))] = v;
    }
    __syncthreads();
    // ownership RMW: wave w handles rows whose class %16 == w (non-atomic:
    // no other wave ever touches those sums rows; in-wave pairs are
    // distinct-class or pre-merged; cross-pair dups safe via LDS program
    // order -- compiler cannot reorder possibly-aliasing LDS accesses).
    const int dd = lane & 31;
    for (int g = 0; g < SUB / 64; ++g) {
      const int c_l = yt[g * 64 + lane];
      const bool mine = ((c_l & 15) == wave) && (c_l < C);
      unsigned long long mask = __ballot(mine);
      while (mask) {
        const int l0 = __builtin_ctzll(mask);
        mask &= mask - 1;
        const int c0 = __shfl(c_l, l0);
        const int r0 = g * 64 + l0;
        if (mask) {
          const int l1 = __builtin_ctzll(mask);
          mask &= mask - 1;
          const int c1 = __shfl(c_l, l1);
          const int r1 = g * 64 + l1;
          if (c0 != c1) {  // both halves RMW distinct classes
            const int cc = (lane < 32) ? c0 : c1;
            const int rr = (lane < 32) ? r0 : r1;
            const int sidx = rr * DC + ((((dd >> 2) ^ (rr & 7)) << 2) | (dd & 3));
            sums[cc * DC + dd] += staged[sidx];
          } else if (lane < 32) {  // same class: pre-merge the two rows
            const int sa = r0 * DC + ((((dd >> 2) ^ (r0 & 7)) << 2) | (dd & 3));
            const int sb = r1 * DC + ((((dd >> 2) ^ (r1 & 7)) << 2) | (dd & 3));
            sums[c0 * DC + dd] += staged[sa] + staged[sb];
          }
        } else if (lane < 32) {  // odd leftover row
          const int sa = r0 * DC + ((((dd >> 2) ^ (r0 & 7)) << 2) | (dd & 3));
          sums[c0 * DC + dd] += staged[sa];
        }
      }
    }
  }

  __syncthreads();
  // transposed dump: partial[c][part][d0+dd] -> reduce reads contiguous
  for (int t = threadIdx.x; t < C * DC; t += AT) {
    const int c = t >> 5;
    const int dd = t & 31;
    partial[((size_t)c * PARTS + part) * D + d0 + dd] = sums[c * DC + dd];
  }
}

__global__ __launch_bounds__(RT) void reduce_kernel(
    const float* __restrict__ partial, const unsigned int* __restrict__ histp,
    const float* __restrict__ centers, const float* __restrict__ counter,
    float* __restrict__ out) {
  const int c = blockIdx.x;
  const int d = threadIdx.x;
  __shared__ unsigned int nsh;
  if (d < 64) {  // count = sum of 64 partition hists (coalesced 256 B)
    unsigned int v = histp[(size_t)c * PARTS + d];
#pragma unroll
    for (int off = 32; off; off >>= 1) v += __shfl_down(v, off, 64);
    if (d == 0) nsh = v;
  }
  __syncthreads();
  const int n = (int)nsh;

  const float* pc = partial + (size_t)c * PARTS * D + d;  // contiguous 32 KB
  float s = 0.f;
#pragma unroll 8
  for (int p = 0; p < PARTS; ++p) s += pc[(size_t)p * D];

  const float cen = centers[c * D + d];
  float o;
  if (n > 0) {
    const float k = counter[0];
    o = (s / (float)n + cen * k) / (k + 1.f);
  } else {
    o = cen;
  }
  out[c * D + d] = o;
}

extern "C" void kernel_launch(void* const* d_in, const int* in_sizes, int n_in,
                              void* d_out, int out_size, void* d_ws, size_t ws_size,
                              hipStream_t stream) {
  const float* x       = (const float*)d_in[0];
  const int* y         = (const int*)d_in[1];
  const float* centers = (const float*)d_in[2];
  const float* counter = (const float*)d_in[3];
  float* out = (float*)d_out;
  const int N = in_sizes[1];

  float* partial      = (float*)d_ws;
  unsigned int* histp = (unsigned int*)((char*)d_ws + (33u << 20));

  hist_kernel<<<dim3(PARTS), dim3(HT), 0, stream>>>(y, histp, N);
  accum_kernel<<<dim3(PARTS * CHUNKS), dim3(AT), 0, stream>>>(x, y, partial, N);
  reduce_kernel<<<dim3(C), dim3(RT), 0, stream>>>(partial, histp, centers,
                                                  counter, out);
}